// Round 1
// baseline (1477.571 us; speedup 1.0000x reference)
//
#include <hip/hip_runtime.h>
#include <stdint.h>

typedef unsigned short u16;
typedef __attribute__((ext_vector_type(4))) float f32x4;
typedef __attribute__((ext_vector_type(8))) short bf16x8;   // 8 bf16 in 4 VGPRs (per guide, compile-verified form)

#define DEVINL __device__ __forceinline__

DEVINL u16 f2bf(float f) {
    union { float f; uint32_t u; } a; a.f = f;
    uint32_t u = a.u;
    uint32_t r = (u + 0x7fffu + ((u >> 16) & 1u)) >> 16;   // RNE
    return (u16)r;
}

// byte offset into a [rows][64 bf16] (128B-row) LDS tile, XOR-swizzled to kill
// the 16-way bank conflict of 128B-stride column reads (G4 / T2-lite).
DEVINL uint32_t swz128(uint32_t row, uint32_t col_byte) {
    return row * 128u + (col_byte ^ ((row & 7u) << 4));
}

// ---------------------------------------------------------------------------
// Kernel A: q/k/v projections.  C[t][n] = act( sum_k x[t][k] * W[n][k] )
// 128x128 tile, BK=64, 4 waves, mfma 16x16x32 bf16, reg-staged fp32->bf16.
// ---------------------------------------------------------------------------
__global__ __launch_bounds__(256) void proj_qkv_kernel(
    const float* __restrict__ x, const float* __restrict__ Wq,
    const float* __restrict__ Wk, const float* __restrict__ Wv,
    u16* __restrict__ qb, u16* __restrict__ kb, u16* __restrict__ vb)
{
    __shared__ __align__(16) char As[128 * 64 * 2];
    __shared__ __align__(16) char Bs[128 * 64 * 2];
    const int bn = blockIdx.x;            // 0..23  (XCD = bn%8 stays fixed)
    const int bm = blockIdx.y;            // 0..127
    const int wsel = bn >> 3;
    const float* __restrict__ W = (wsel == 0) ? Wq : ((wsel == 1) ? Wk : Wv);
    u16* __restrict__ dst = (wsel == 0) ? qb : ((wsel == 1) ? kb : vb);
    const int cb = (bn & 7) * 128;
    const int rb = bm * 128;
    const int tid = threadIdx.x;
    const int lane = tid & 63;
    const int wv = tid >> 6;
    const int wr = (wv >> 1) * 64, wc = (wv & 1) * 64;
    const int li = lane & 15, g = lane >> 4;

    f32x4 acc[4][4];
#pragma unroll
    for (int i = 0; i < 4; ++i)
#pragma unroll
        for (int j = 0; j < 4; ++j) acc[i][j] = (f32x4)0.0f;

    for (int k0 = 0; k0 < 1024; k0 += 64) {
        __syncthreads();
#pragma unroll
        for (int p = 0; p < 8; ++p) {
            int id = p * 256 + tid;          // 0..2047
            int row = id >> 4;               // 0..127
            int c4 = id & 15;
            float4 va = *(const float4*)(x + (size_t)(rb + row) * 1024 + k0 + c4 * 4);
            uint2 pa;
            pa.x = (uint32_t)f2bf(va.x) | ((uint32_t)f2bf(va.y) << 16);
            pa.y = (uint32_t)f2bf(va.z) | ((uint32_t)f2bf(va.w) << 16);
            *(uint2*)(As + swz128(row, c4 * 8)) = pa;
            float4 vb4 = *(const float4*)(W + (size_t)(cb + row) * 1024 + k0 + c4 * 4);
            uint2 pb;
            pb.x = (uint32_t)f2bf(vb4.x) | ((uint32_t)f2bf(vb4.y) << 16);
            pb.y = (uint32_t)f2bf(vb4.z) | ((uint32_t)f2bf(vb4.w) << 16);
            *(uint2*)(Bs + swz128(row, c4 * 8)) = pb;
        }
        __syncthreads();
#pragma unroll
        for (int ks = 0; ks < 2; ++ks) {
            bf16x8 af[4], bfr[4];
#pragma unroll
            for (int m = 0; m < 4; ++m)
                af[m] = *(const bf16x8*)(As + swz128(wr + m * 16 + li, ks * 64 + g * 16));
#pragma unroll
            for (int n = 0; n < 4; ++n)
                bfr[n] = *(const bf16x8*)(Bs + swz128(wc + n * 16 + li, ks * 64 + g * 16));
#pragma unroll
            for (int m = 0; m < 4; ++m)
#pragma unroll
                for (int n = 0; n < 4; ++n)
                    acc[m][n] = __builtin_amdgcn_mfma_f32_16x16x32_bf16(af[m], bfr[n], acc[m][n], 0, 0, 0);
        }
    }
    const bool do_silu = (wsel < 2);
#pragma unroll
    for (int m = 0; m < 4; ++m) {
        int t = rb + wr + m * 16 + g * 4;
#pragma unroll
        for (int r = 0; r < 4; ++r) {
#pragma unroll
            for (int n = 0; n < 4; ++n) {
                float v = acc[m][n][r];
                if (do_silu) v = v / (1.0f + __expf(-v));
                int col = cb + wc + n * 16 + li;
                dst[(size_t)(t + r) * 1024 + col] = f2bf(v);
            }
        }
    }
}

// ---------------------------------------------------------------------------
// Kernel B: lr/wd heads.  lrwd[t][c] : c<32 -> sigmoid(x.Wlr[c])*1e-3,
//                                      c>=32 -> sigmoid(x.Wbeta[c-32])*0.9
// ---------------------------------------------------------------------------
__global__ __launch_bounds__(256) void lrwd_kernel(
    const float* __restrict__ x, const float* __restrict__ Wlr,
    const float* __restrict__ Wbeta, float* __restrict__ lrwd)
{
    __shared__ __align__(16) float xs[16][1024];
    const int t0 = blockIdx.x * 16;
    const int tid = threadIdx.x;
#pragma unroll
    for (int p = 0; p < 16; ++p) {
        int id = p * 256 + tid;            // float4 id, 0..4095
        int row = id >> 8;
        int c4 = id & 255;
        *(float4*)&xs[row][c4 * 4] = *(const float4*)(x + (size_t)(t0 + row) * 1024 + c4 * 4);
    }
    __syncthreads();
    const int token = tid >> 4;
    const int cl = tid & 15;
#pragma unroll
    for (int pp = 0; pp < 4; ++pp) {
        int col = pp * 16 + cl;            // 0..63
        const float* wrow = (col < 32) ? (Wlr + (size_t)col * 1024) : (Wbeta + (size_t)(col - 32) * 1024);
        float s = 0.f;
        for (int k = 0; k < 1024; k += 4) {
            float4 xv = *(const float4*)&xs[token][k];
            float4 wv = *(const float4*)(wrow + k);
            s += xv.x * wv.x + xv.y * wv.y + xv.z * wv.z + xv.w * wv.w;
        }
        float sg = 1.0f / (1.0f + __expf(-s));
        lrwd[(size_t)(t0 + token) * 64 + col] = sg * ((col < 32) ? 1e-3f : 0.9f);
    }
}

// ---------------------------------------------------------------------------
// Kernel C: the chunk scan.  One block per (b,h); 4 waves; 64 chunks serial.
// All matmuls are 64x64x64 via mfma 16x16x32 bf16 through swizzled LDS.
// Orientation trick: S^T (rows=D, cols=n) makes softmax-over-n wave-local.
// ---------------------------------------------------------------------------
__global__ __launch_bounds__(256) void scan_kernel(
    const u16* __restrict__ qb, const u16* __restrict__ kb, const u16* __restrict__ vb,
    const float* __restrict__ lrwd, const float* __restrict__ Wi0,
    const float* __restrict__ Wo0, u16* __restrict__ ob)
{
    const int bh = blockIdx.x;
    const int b = bh >> 4, h = bh & 15;
    const int tid = threadIdx.x;
    const int lane = tid & 63;
    const int w = tid >> 6;
    const int li = lane & 15, g = lane >> 4;

    __shared__ float WiF[64 * 64];
    __shared__ float WoF[64 * 64];
    __shared__ __align__(16) char WiB[8192], WoB[8192], WoT[8192];
    __shared__ __align__(16) char Qc[8192], Kc[8192], KcT[8192], Vc[8192], VcT[8192];
    __shared__ __align__(16) char PQ[8192], PT[8192], GZT[8192];
    __shared__ float spart[4 * 64];
    __shared__ float lrc[64 * 4];

    // ---- init state (W_in_init/W_out_init are (1,64,16,64): elem (D,h,d)) ----
    {
        int D = tid >> 2, d0 = (tid & 3) * 16;
        const float* si = Wi0 + ((size_t)D * 16 + h) * 64 + d0;
        const float* so = Wo0 + ((size_t)D * 16 + h) * 64 + d0;
#pragma unroll
        for (int j = 0; j < 16; ++j) {
            float vi_ = si[j], vo_ = so[j];
            int d = d0 + j;
            WiF[D * 64 + d] = vi_;
            WoF[D * 64 + d] = vo_;
            *(u16*)(WiB + swz128(D, d * 2)) = f2bf(vi_);
            *(u16*)(WoB + swz128(D, d * 2)) = f2bf(vo_);
            *(u16*)(WoT + swz128(d, D * 2)) = f2bf(vo_);
        }
    }
    // ---- per-chunk lr/wd means ----
    {
        int cc = tid >> 2, j = tid & 3;
        const float* src = lrwd + ((size_t)(b * 4096 + cc * 64)) * 64 + j * 16 + h;
        float s = 0.f;
        for (int n = 0; n < 64; ++n) s += src[(size_t)n * 64];
        lrc[cc * 4 + j] = s * (1.0f / 64.0f);
    }

    auto stage = [&](int c) {
        const size_t base = ((size_t)(b * 4096 + c * 64)) * 1024 + h * 64;
#pragma unroll
        for (int p = 0; p < 2; ++p) {
            int id = p * 256 + tid;          // 0..511
            int n = id >> 3;                 // 0..63
            int d0 = (id & 7) * 8;
            uint4 qv = *(const uint4*)(qb + base + (size_t)n * 1024 + d0);
            *(uint4*)(Qc + swz128(n, d0 * 2)) = qv;
            uint4 kv = *(const uint4*)(kb + base + (size_t)n * 1024 + d0);
            *(uint4*)(Kc + swz128(n, d0 * 2)) = kv;
            uint4 vv = *(const uint4*)(vb + base + (size_t)n * 1024 + d0);
            *(uint4*)(Vc + swz128(n, d0 * 2)) = vv;
            const u16* ks_ = (const u16*)&kv;
            const u16* vs_ = (const u16*)&vv;
#pragma unroll
            for (int j = 0; j < 8; ++j) {
                int d = d0 + j;
                *(u16*)(KcT + swz128(d, n * 2)) = ks_[j];
                *(u16*)(VcT + swz128(d, n * 2)) = vs_[j];
            }
        }
    };

    stage(0);
    __syncthreads();

    for (int c = 0; c < 64; ++c) {
        // ---- M1: Sq^T[D][n] = sum_d Wi[D][d] q[n][d]; softmax over n; -> PQ[n][D]
        f32x4 sq[4];
        {
            bf16x8 a0 = *(const bf16x8*)(WiB + swz128(w * 16 + li, g * 16));
            bf16x8 a1 = *(const bf16x8*)(WiB + swz128(w * 16 + li, 64 + g * 16));
#pragma unroll
            for (int tn = 0; tn < 4; ++tn) {
                bf16x8 b0 = *(const bf16x8*)(Qc + swz128(tn * 16 + li, g * 16));
                bf16x8 b1 = *(const bf16x8*)(Qc + swz128(tn * 16 + li, 64 + g * 16));
                f32x4 z = (f32x4)0.0f;
                z = __builtin_amdgcn_mfma_f32_16x16x32_bf16(a0, b0, z, 0, 0, 0);
                z = __builtin_amdgcn_mfma_f32_16x16x32_bf16(a1, b1, z, 0, 0, 0);
                sq[tn] = z;
            }
        }
#pragma unroll
        for (int r = 0; r < 4; ++r) {
            float m = fmaxf(fmaxf(sq[0][r], sq[1][r]), fmaxf(sq[2][r], sq[3][r]));
            m = fmaxf(m, __shfl_xor(m, 1)); m = fmaxf(m, __shfl_xor(m, 2));
            m = fmaxf(m, __shfl_xor(m, 4)); m = fmaxf(m, __shfl_xor(m, 8));
            float e0 = __expf(sq[0][r] - m), e1 = __expf(sq[1][r] - m);
            float e2 = __expf(sq[2][r] - m), e3 = __expf(sq[3][r] - m);
            float s = e0 + e1 + e2 + e3;
            s += __shfl_xor(s, 1); s += __shfl_xor(s, 2);
            s += __shfl_xor(s, 4); s += __shfl_xor(s, 8);
            float inv = 1.0f / s;
            sq[0][r] = e0 * inv; sq[1][r] = e1 * inv; sq[2][r] = e2 * inv; sq[3][r] = e3 * inv;
        }
#pragma unroll
        for (int tn = 0; tn < 4; ++tn) {   // transposed pack: 4 rows -> one b64
            int n = tn * 16 + li;
            uint2 pw;
            pw.x = (uint32_t)f2bf(sq[tn][0]) | ((uint32_t)f2bf(sq[tn][1]) << 16);
            pw.y = (uint32_t)f2bf(sq[tn][2]) | ((uint32_t)f2bf(sq[tn][3]) << 16);
            *(uint2*)(PQ + swz128(n, (w * 16 + g * 4) * 2)) = pw;
        }

        // ---- M2: Sk^T -> p^T (kept in regs) ----
        f32x4 pk[4];
        {
            bf16x8 a0 = *(const bf16x8*)(WiB + swz128(w * 16 + li, g * 16));
            bf16x8 a1 = *(const bf16x8*)(WiB + swz128(w * 16 + li, 64 + g * 16));
#pragma unroll
            for (int tn = 0; tn < 4; ++tn) {
                bf16x8 b0 = *(const bf16x8*)(Kc + swz128(tn * 16 + li, g * 16));
                bf16x8 b1 = *(const bf16x8*)(Kc + swz128(tn * 16 + li, 64 + g * 16));
                f32x4 z = (f32x4)0.0f;
                z = __builtin_amdgcn_mfma_f32_16x16x32_bf16(a0, b0, z, 0, 0, 0);
                z = __builtin_amdgcn_mfma_f32_16x16x32_bf16(a1, b1, z, 0, 0, 0);
                pk[tn] = z;
            }
        }
#pragma unroll
        for (int r = 0; r < 4; ++r) {
            float m = fmaxf(fmaxf(pk[0][r], pk[1][r]), fmaxf(pk[2][r], pk[3][r]));
            m = fmaxf(m, __shfl_xor(m, 1)); m = fmaxf(m, __shfl_xor(m, 2));
            m = fmaxf(m, __shfl_xor(m, 4)); m = fmaxf(m, __shfl_xor(m, 8));
            float e0 = __expf(pk[0][r] - m), e1 = __expf(pk[1][r] - m);
            float e2 = __expf(pk[2][r] - m), e3 = __expf(pk[3][r] - m);
            float s = e0 + e1 + e2 + e3;
            s += __shfl_xor(s, 1); s += __shfl_xor(s, 2);
            s += __shfl_xor(s, 4); s += __shfl_xor(s, 8);
            float inv = 1.0f / s;
            pk[0][r] = e0 * inv; pk[1][r] = e1 * inv; pk[2][r] = e2 * inv; pk[3][r] = e3 * inv;
        }

        // ---- M4': a^T[D][n] = sum_d Wo[D][d] v[n][d] ----
        f32x4 aT[4];
        {
            bf16x8 a0 = *(const bf16x8*)(WoB + swz128(w * 16 + li, g * 16));
            bf16x8 a1 = *(const bf16x8*)(WoB + swz128(w * 16 + li, 64 + g * 16));
#pragma unroll
            for (int tn = 0; tn < 4; ++tn) {
                bf16x8 b0 = *(const bf16x8*)(Vc + swz128(tn * 16 + li, g * 16));
                bf16x8 b1 = *(const bf16x8*)(Vc + swz128(tn * 16 + li, 64 + g * 16));
                f32x4 z = (f32x4)0.0f;
                z = __builtin_amdgcn_mfma_f32_16x16x32_bf16(a0, b0, z, 0, 0, 0);
                z = __builtin_amdgcn_mfma_f32_16x16x32_bf16(a1, b1, z, 0, 0, 0);
                aT[tn] = z;
            }
        }
        // ---- s[n] = sum_D p*a : partial over this wave's 16 D-rows ----
#pragma unroll
        for (int tn = 0; tn < 4; ++tn) {
            f32x4 t4 = pk[tn] * aT[tn];
            float s_ = t4[0] + t4[1] + t4[2] + t4[3];
            s_ += __shfl_xor(s_, 16);
            s_ += __shfl_xor(s_, 32);
            if (g == 0) spart[w * 64 + tn * 16 + li] = s_;
        }
        __syncthreads();   // B: spart, PQ visible

        // ---- gz^T = p^T * (s - a^T) ; write GZT[D][n], PT[D][n] ----
#pragma unroll
        for (int tn = 0; tn < 4; ++tn) {
            int n = tn * 16 + li;
            float sn = spart[n] + spart[64 + n] + spart[128 + n] + spart[192 + n];
#pragma unroll
            for (int r = 0; r < 4; ++r) {
                int D = w * 16 + g * 4 + r;
                float gz = pk[tn][r] * (sn - aT[tn][r]);
                *(u16*)(GZT + swz128(D, n * 2)) = f2bf(gz);
                *(u16*)(PT + swz128(D, n * 2)) = f2bf(pk[tn][r]);
            }
        }
        __syncthreads();   // C: GZT, PT visible

        // ---- M3: o[n][d] = sum_D pq[n][D] Wo[D][d]  (B = WoT[d][D]) ----
        f32x4 o4[4];
        {
            bf16x8 a0 = *(const bf16x8*)(PQ + swz128(w * 16 + li, g * 16));
            bf16x8 a1 = *(const bf16x8*)(PQ + swz128(w * 16 + li, 64 + g * 16));
#pragma unroll
            for (int tn = 0; tn < 4; ++tn) {
                bf16x8 b0 = *(const bf16x8*)(WoT + swz128(tn * 16 + li, g * 16));
                bf16x8 b1 = *(const bf16x8*)(WoT + swz128(tn * 16 + li, 64 + g * 16));
                f32x4 z = (f32x4)0.0f;
                z = __builtin_amdgcn_mfma_f32_16x16x32_bf16(a0, b0, z, 0, 0, 0);
                z = __builtin_amdgcn_mfma_f32_16x16x32_bf16(a1, b1, z, 0, 0, 0);
                o4[tn] = z;
            }
        }
        {
            const size_t obase = ((size_t)(b * 4096 + c * 64)) * 1024 + h * 64;
#pragma unroll
            for (int tn = 0; tn < 4; ++tn) {
                int d = tn * 16 + li;
#pragma unroll
                for (int r = 0; r < 4; ++r) {
                    int n = w * 16 + g * 4 + r;
                    ob[obase + (size_t)n * 1024 + d] = f2bf(o4[tn][r]);
                }
            }
        }
        // ---- M5: go[D][d] = sum_n p[n][D] v[n][d]  ( = -grad_out ) ----
        f32x4 go[4];
        {
            bf16x8 a0 = *(const bf16x8*)(PT + swz128(w * 16 + li, g * 16));
            bf16x8 a1 = *(const bf16x8*)(PT + swz128(w * 16 + li, 64 + g * 16));
#pragma unroll
            for (int tn = 0; tn < 4; ++tn) {
                bf16x8 b0 = *(const bf16x8*)(VcT + swz128(tn * 16 + li, g * 16));
                bf16x8 b1 = *(const bf16x8*)(VcT + swz128(tn * 16 + li, 64 + g * 16));
                f32x4 z = (f32x4)0.0f;
                z = __builtin_amdgcn_mfma_f32_16x16x32_bf16(a0, b0, z, 0, 0, 0);
                z = __builtin_amdgcn_mfma_f32_16x16x32_bf16(a1, b1, z, 0, 0, 0);
                go[tn] = z;
            }
        }
        // ---- M6: gi[D][d] = sum_n gz[n][D] k[n][d]  ( = grad_in ) ----
        f32x4 gi[4];
        {
            bf16x8 a0 = *(const bf16x8*)(GZT + swz128(w * 16 + li, g * 16));
            bf16x8 a1 = *(const bf16x8*)(GZT + swz128(w * 16 + li, 64 + g * 16));
#pragma unroll
            for (int tn = 0; tn < 4; ++tn) {
                bf16x8 b0 = *(const bf16x8*)(KcT + swz128(tn * 16 + li, g * 16));
                bf16x8 b1 = *(const bf16x8*)(KcT + swz128(tn * 16 + li, 64 + g * 16));
                f32x4 z = (f32x4)0.0f;
                z = __builtin_amdgcn_mfma_f32_16x16x32_bf16(a0, b0, z, 0, 0, 0);
                z = __builtin_amdgcn_mfma_f32_16x16x32_bf16(a1, b1, z, 0, 0, 0);
                gi[tn] = z;
            }
        }
        __syncthreads();   // D: all reads of W*/P*/GZT/Qc.. complete

        // ---- state update (pre-update values were used above) ----
        {
            float lin = lrc[c * 4 + 0], lout = lrc[c * 4 + 1];
            float win = lrc[c * 4 + 2], wout = lrc[c * 4 + 3];
#pragma unroll
            for (int tn = 0; tn < 4; ++tn) {
                int d = tn * 16 + li;
#pragma unroll
                for (int r = 0; r < 4; ++r) {
                    int D = w * 16 + g * 4 + r;
                    float nwi = win * WiF[D * 64 + d] - lin * gi[tn][r];
                    WiF[D * 64 + d] = nwi;
                    *(u16*)(WiB + swz128(D, d * 2)) = f2bf(nwi);
                    float nwo = wout * WoF[D * 64 + d] + lout * go[tn][r];  // grad_out = -go
                    WoF[D * 64 + d] = nwo;
                    *(u16*)(WoB + swz128(D, d * 2)) = f2bf(nwo);
                    *(u16*)(WoT + swz128(d, D * 2)) = f2bf(nwo);
                }
            }
        }
        if (c + 1 < 64) stage(c + 1);
        __syncthreads();   // A: next chunk ready
    }
}

// ---------------------------------------------------------------------------
// Kernel D: out[t][m] = sum_j o[t][j] * Wo[m][j]   (fp32 out)
// ---------------------------------------------------------------------------
__global__ __launch_bounds__(256) void out_proj_kernel(
    const u16* __restrict__ ob, const float* __restrict__ Wo, float* __restrict__ out)
{
    __shared__ __align__(16) char As[128 * 64 * 2];
    __shared__ __align__(16) char Bs[128 * 64 * 2];
    const int bn = blockIdx.x;            // 0..7
    const int bm = blockIdx.y;            // 0..127
    const int cb = bn * 128;
    const int rb = bm * 128;
    const int tid = threadIdx.x;
    const int lane = tid & 63;
    const int wv = tid >> 6;
    const int wr = (wv >> 1) * 64, wc = (wv & 1) * 64;
    const int li = lane & 15, g = lane >> 4;

    f32x4 acc[4][4];
#pragma unroll
    for (int i = 0; i < 4; ++i)
#pragma unroll
        for (int j = 0; j < 4; ++j) acc[i][j] = (f32x4)0.0f;

    for (int k0 = 0; k0 < 1024; k0 += 64) {
        __syncthreads();
#pragma unroll
        for (int p = 0; p < 4; ++p) {      // A tile: bf16, 1024 x 16B
            int id = p * 256 + tid;
            int row = id >> 3;
            int c16 = id & 7;
            uint4 v = *(const uint4*)(ob + (size_t)(rb + row) * 1024 + k0 + c16 * 8);
            *(uint4*)(As + swz128(row, c16 * 16)) = v;
        }
#pragma unroll
        for (int p = 0; p < 8; ++p) {      // B tile: fp32 -> bf16
            int id = p * 256 + tid;
            int row = id >> 4;
            int c4 = id & 15;
            float4 vb4 = *(const float4*)(Wo + (size_t)(cb + row) * 1024 + k0 + c4 * 4);
            uint2 pb;
            pb.x = (uint32_t)f2bf(vb4.x) | ((uint32_t)f2bf(vb4.y) << 16);
            pb.y = (uint32_t)f2bf(vb4.z) | ((uint32_t)f2bf(vb4.w) << 16);
            *(uint2*)(Bs + swz128(row, c4 * 8)) = pb;
        }
        __syncthreads();
#pragma unroll
        for (int ks = 0; ks < 2; ++ks) {
            bf16x8 af[4], bfr[4];
#pragma unroll
            for (int m = 0; m < 4; ++m)
                af[m] = *(const bf16x8*)(As + swz128(wr + m * 16 + li, ks * 64 + g * 16));
#pragma unroll
            for (int n = 0; n < 4; ++n)
                bfr[n] = *(const bf16x8*)(Bs + swz128(wc + n * 16 + li, ks * 64 + g * 16));
#pragma unroll
            for (int m = 0; m < 4; ++m)
#pragma unroll
                for (int n = 0; n < 4; ++n)
                    acc[m][n] = __builtin_amdgcn_mfma_f32_16x16x32_bf16(af[m], bfr[n], acc[m][n], 0, 0, 0);
        }
    }
#pragma unroll
    for (int m = 0; m < 4; ++m) {
        int t = rb + wr + m * 16 + g * 4;
#pragma unroll
        for (int r = 0; r < 4; ++r) {
#pragma unroll
            for (int n = 0; n < 4; ++n) {
                int col = cb + wc + n * 16 + li;
                out[(size_t)(t + r) * 1024 + col] = acc[m][n][r];
            }
        }
    }
}

// ---------------------------------------------------------------------------
extern "C" void kernel_launch(void* const* d_in, const int* in_sizes, int n_in,
                              void* d_out, int out_size, void* d_ws, size_t ws_size,
                              hipStream_t stream)
{
    const float* x     = (const float*)d_in[0];
    const float* Wq    = (const float*)d_in[1];
    const float* Wk    = (const float*)d_in[2];
    const float* Wv    = (const float*)d_in[3];
    const float* Wlr   = (const float*)d_in[4];
    const float* Wbeta = (const float*)d_in[5];
    const float* Wo    = (const float*)d_in[6];
    const float* Wi0   = (const float*)d_in[7];
    const float* Wo0   = (const float*)d_in[8];
    float* out = (float*)d_out;

    char* ws = (char*)d_ws;
    u16* qb   = (u16*)(ws);
    u16* kb   = (u16*)(ws + 33554432u);
    u16* vb   = (u16*)(ws + 67108864u);
    u16* obuf = (u16*)(ws + 100663296u);
    float* lrwd = (float*)(ws + 134217728u);
    if (ws_size < 138412032u) return;   // need ~132 MB scratch

    proj_qkv_kernel<<<dim3(24, 128), 256, 0, stream>>>(x, Wq, Wk, Wv, qb, kb, vb);
    lrwd_kernel<<<1024, 256, 0, stream>>>(x, Wlr, Wbeta, lrwd);
    scan_kernel<<<64, 256, 0, stream>>>(qb, kb, vb, lrwd, Wi0, Wo0, obuf);
    out_proj_kernel<<<dim3(8, 128), 256, 0, stream>>>(obuf, Wo, out);
}

// Round 2
// 675.414 us; speedup vs baseline: 2.1877x; 2.1877x over previous
//
#include <hip/hip_runtime.h>
#include <stdint.h>

typedef unsigned short u16;
typedef __attribute__((ext_vector_type(4))) float f32x4;
typedef __attribute__((ext_vector_type(8))) short bf16x8;

#define DEVINL __device__ __forceinline__

DEVINL u16 f2bf(float f) {
    union { float f; uint32_t u; } a; a.f = f;
    uint32_t u = a.u;
    uint32_t r = (u + 0x7fffu + ((u >> 16) & 1u)) >> 16;   // RNE
    return (u16)r;
}

DEVINL uint32_t swz128(uint32_t row, uint32_t col_byte) {
    return row * 128u + (col_byte ^ ((row & 7u) << 4));
}

// async global->LDS, 16B per lane, wave-uniform LDS base (lane i lands at base+i*16)
DEVINL void gload_lds16(const u16* g, char* l) {
    __builtin_amdgcn_global_load_lds(
        (const __attribute__((address_space(1))) void*)g,
        (__attribute__((address_space(3))) void*)l, 16, 0, 0);
}

// ---------------------------------------------------------------------------
// Kernel 0: fp32 -> bf16 convert pass (x, Wq|Wk|Wv concat, Wo, Wlr|Wbeta concat)
// ---------------------------------------------------------------------------
__global__ __launch_bounds__(256) void convert_kernel(
    const float* __restrict__ x, const float* __restrict__ Wq,
    const float* __restrict__ Wk, const float* __restrict__ Wv,
    const float* __restrict__ Wo, const float* __restrict__ Wlr,
    const float* __restrict__ Wbeta,
    u16* __restrict__ xb, u16* __restrict__ wb, u16* __restrict__ wob,
    u16* __restrict__ wlb)
{
    const int t0 = blockIdx.x * 256 + threadIdx.x;
    const int stride = gridDim.x * 256;
    auto cv = [&](const float* src, u16* dst, int n4) {
        for (int i = t0; i < n4; i += stride) {
            float4 v = ((const float4*)src)[i];
            uint2 p;
            p.x = (uint32_t)f2bf(v.x) | ((uint32_t)f2bf(v.y) << 16);
            p.y = (uint32_t)f2bf(v.z) | ((uint32_t)f2bf(v.w) << 16);
            ((uint2*)dst)[i] = p;
        }
    };
    cv(x, xb, 4194304);
    cv(Wq, wb, 262144);
    cv(Wk, wb + 1048576, 262144);
    cv(Wv, wb + 2097152, 262144);
    cv(Wo, wob, 262144);
    cv(Wlr, wlb, 8192);
    cv(Wbeta, wlb + 32768, 8192);
}

// ---------------------------------------------------------------------------
// Kernel A: q/k/v projections (bf16 in, bf16 out, fused silu for q,k).
// m97 structure: 128x128 tile, BK=64, global_load_lds x16, linear LDS.
// ---------------------------------------------------------------------------
__global__ __launch_bounds__(256) void proj_qkv_kernel(
    const u16* __restrict__ xb, const u16* __restrict__ wb,
    u16* __restrict__ qb, u16* __restrict__ kb, u16* __restrict__ vb)
{
    __shared__ __align__(16) char As[128 * 128];
    __shared__ __align__(16) char Bs[128 * 128];
    const int bn = blockIdx.x;            // 0..23
    const int bm = blockIdx.y;            // 0..127
    const int wsel = bn >> 3;
    u16* __restrict__ dst = (wsel == 0) ? qb : ((wsel == 1) ? kb : vb);
    const int cb = (bn & 7) * 128;        // output col block within 1024
    const int wrow = bn * 128;            // row within concat weights (3072)
    const int rb = bm * 128;
    const int tid = threadIdx.x;
    const int lane = tid & 63;
    const int wv = tid >> 6;
    const int wr = (wv >> 1) * 64, wc = (wv & 1) * 64;
    const int li = lane & 15, g = lane >> 4;
    const int lr8 = lane >> 3, lc8 = lane & 7;

    f32x4 acc[4][4];
#pragma unroll
    for (int i = 0; i < 4; ++i)
#pragma unroll
        for (int j = 0; j < 4; ++j) acc[i][j] = (f32x4)0.0f;

    for (int k0 = 0; k0 < 1024; k0 += 64) {
        __syncthreads();
#pragma unroll
        for (int ld = 0; ld < 4; ++ld) {
            int r0 = wv * 32 + ld * 8;
            gload_lds16(xb + (size_t)(rb + r0 + lr8) * 1024 + k0 + lc8 * 8, As + r0 * 128);
            gload_lds16(wb + (size_t)(wrow + r0 + lr8) * 1024 + k0 + lc8 * 8, Bs + r0 * 128);
        }
        __syncthreads();
#pragma unroll
        for (int ks = 0; ks < 2; ++ks) {
            bf16x8 af[4], bfr[4];
#pragma unroll
            for (int m = 0; m < 4; ++m)
                af[m] = *(const bf16x8*)(As + (wr + m * 16 + li) * 128 + ks * 64 + g * 16);
#pragma unroll
            for (int n = 0; n < 4; ++n)
                bfr[n] = *(const bf16x8*)(Bs + (wc + n * 16 + li) * 128 + ks * 64 + g * 16);
#pragma unroll
            for (int m = 0; m < 4; ++m)
#pragma unroll
                for (int n = 0; n < 4; ++n)
                    acc[m][n] = __builtin_amdgcn_mfma_f32_16x16x32_bf16(af[m], bfr[n], acc[m][n], 0, 0, 0);
        }
    }
    const bool do_silu = (wsel < 2);
#pragma unroll
    for (int m = 0; m < 4; ++m) {
        int t = rb + wr + m * 16 + g * 4;
#pragma unroll
        for (int r = 0; r < 4; ++r) {
#pragma unroll
            for (int n = 0; n < 4; ++n) {
                float v = acc[m][n][r];
                if (do_silu) v = v / (1.0f + __expf(-v));
                int col = cb + wc + n * 16 + li;
                dst[(size_t)(t + r) * 1024 + col] = f2bf(v);
            }
        }
    }
}

// ---------------------------------------------------------------------------
// Kernel B: lr/wd heads as 128x64 MFMA GEMM + on-chip per-chunk mean.
// Output: lrc_all[b][64 chunks][64 cols] fp32 (col<32: lr*1e-3, col>=32: wd*0.9)
// ---------------------------------------------------------------------------
__global__ __launch_bounds__(256) void lrwd_kernel(
    const u16* __restrict__ xb, const u16* __restrict__ wlb,
    float* __restrict__ lrc_all)
{
    __shared__ __align__(16) char As[128 * 128];
    __shared__ __align__(16) char Bs[64 * 128];
    __shared__ float red[128][65];
    const int bm = blockIdx.x;            // 0..127
    const int rb = bm * 128;
    const int tid = threadIdx.x;
    const int lane = tid & 63;
    const int wv = tid >> 6;
    const int li = lane & 15, g = lane >> 4;
    const int lr8 = lane >> 3, lc8 = lane & 7;

    f32x4 acc[2][4];
#pragma unroll
    for (int i = 0; i < 2; ++i)
#pragma unroll
        for (int j = 0; j < 4; ++j) acc[i][j] = (f32x4)0.0f;

    for (int k0 = 0; k0 < 1024; k0 += 64) {
        __syncthreads();
#pragma unroll
        for (int ld = 0; ld < 4; ++ld) {
            int r0 = wv * 32 + ld * 8;
            gload_lds16(xb + (size_t)(rb + r0 + lr8) * 1024 + k0 + lc8 * 8, As + r0 * 128);
        }
#pragma unroll
        for (int ld = 0; ld < 2; ++ld) {
            int r0 = wv * 16 + ld * 8;
            gload_lds16(wlb + (size_t)(r0 + lr8) * 1024 + k0 + lc8 * 8, Bs + r0 * 128);
        }
        __syncthreads();
#pragma unroll
        for (int ks = 0; ks < 2; ++ks) {
            bf16x8 af[2], bfr[4];
#pragma unroll
            for (int m = 0; m < 2; ++m)
                af[m] = *(const bf16x8*)(As + (wv * 32 + m * 16 + li) * 128 + ks * 64 + g * 16);
#pragma unroll
            for (int n = 0; n < 4; ++n)
                bfr[n] = *(const bf16x8*)(Bs + (n * 16 + li) * 128 + ks * 64 + g * 16);
#pragma unroll
            for (int m = 0; m < 2; ++m)
#pragma unroll
                for (int n = 0; n < 4; ++n)
                    acc[m][n] = __builtin_amdgcn_mfma_f32_16x16x32_bf16(af[m], bfr[n], acc[m][n], 0, 0, 0);
        }
    }
#pragma unroll
    for (int m = 0; m < 2; ++m) {
#pragma unroll
        for (int n = 0; n < 4; ++n) {
            int col = n * 16 + li;
            float scale = (col < 32) ? 1e-3f : 0.9f;
#pragma unroll
            for (int r = 0; r < 4; ++r) {
                int t = wv * 32 + m * 16 + g * 4 + r;
                float s = acc[m][n][r];
                red[t][col] = scale / (1.0f + __expf(-s));
            }
        }
    }
    __syncthreads();
    if (tid < 128) {
        int chunk = tid >> 6, col = tid & 63;
        float s = 0.f;
#pragma unroll
        for (int i = 0; i < 64; ++i) s += red[chunk * 64 + i][col];
        int b = bm >> 5;
        int cidx = (bm & 31) * 2 + chunk;
        lrc_all[((size_t)(b * 64 + cidx)) * 64 + col] = s * (1.0f / 64.0f);
    }
}

// ---------------------------------------------------------------------------
// Kernel C: the chunk scan.  One block per (b,h); 4 waves; 64 chunks serial.
// T14: prefetch next chunk's q/k/v to regs at chunk start, commit to LDS at end.
// ---------------------------------------------------------------------------
__global__ __launch_bounds__(256) void scan_kernel(
    const u16* __restrict__ qb, const u16* __restrict__ kb, const u16* __restrict__ vb,
    const float* __restrict__ lrc_all, const float* __restrict__ Wi0,
    const float* __restrict__ Wo0, u16* __restrict__ ob)
{
    const int bh = blockIdx.x;
    const int b = bh >> 4, h = bh & 15;
    const int tid = threadIdx.x;
    const int lane = tid & 63;
    const int w = tid >> 6;
    const int li = lane & 15, g = lane >> 4;

    __shared__ float WiF[64 * 64];
    __shared__ float WoF[64 * 64];
    __shared__ __align__(16) char WiB[8192], WoB[8192], WoT[8192];
    __shared__ __align__(16) char Qc[8192], Kc[8192], KcT[8192], Vc[8192], VcT[8192];
    __shared__ __align__(16) char PQ[8192], PT[8192], GZT[8192];
    __shared__ float spart[4 * 64];
    __shared__ float lrc[64 * 4];

    {
        int D = tid >> 2, d0 = (tid & 3) * 16;
        const float* si = Wi0 + ((size_t)D * 16 + h) * 64 + d0;
        const float* so = Wo0 + ((size_t)D * 16 + h) * 64 + d0;
#pragma unroll
        for (int j = 0; j < 16; ++j) {
            float vi_ = si[j], vo_ = so[j];
            int d = d0 + j;
            WiF[D * 64 + d] = vi_;
            WoF[D * 64 + d] = vo_;
            *(u16*)(WiB + swz128(D, d * 2)) = f2bf(vi_);
            *(u16*)(WoB + swz128(D, d * 2)) = f2bf(vo_);
            *(u16*)(WoT + swz128(d, D * 2)) = f2bf(vo_);
        }
    }
    {
        int cc = tid >> 2, j = tid & 3;
        lrc[cc * 4 + j] = lrc_all[((size_t)(b * 64 + cc)) * 64 + j * 16 + h];
    }

    uint4 pfq[2], pfk[2], pfv[2];
    auto prefetch = [&](int c) {
        const size_t base = ((size_t)(b * 4096 + c * 64)) * 1024 + h * 64;
#pragma unroll
        for (int p = 0; p < 2; ++p) {
            int id = p * 256 + tid;
            int n = id >> 3;
            int d0 = (id & 7) * 8;
            pfq[p] = *(const uint4*)(qb + base + (size_t)n * 1024 + d0);
            pfk[p] = *(const uint4*)(kb + base + (size_t)n * 1024 + d0);
            pfv[p] = *(const uint4*)(vb + base + (size_t)n * 1024 + d0);
        }
    };
    auto commit = [&]() {
#pragma unroll
        for (int p = 0; p < 2; ++p) {
            int id = p * 256 + tid;
            int n = id >> 3;
            int d0 = (id & 7) * 8;
            *(uint4*)(Qc + swz128(n, d0 * 2)) = pfq[p];
            *(uint4*)(Kc + swz128(n, d0 * 2)) = pfk[p];
            *(uint4*)(Vc + swz128(n, d0 * 2)) = pfv[p];
            const u16* ks_ = (const u16*)&pfk[p];
            const u16* vs_ = (const u16*)&pfv[p];
#pragma unroll
            for (int j = 0; j < 8; ++j) {
                int d = d0 + j;
                *(u16*)(KcT + swz128(d, n * 2)) = ks_[j];
                *(u16*)(VcT + swz128(d, n * 2)) = vs_[j];
            }
        }
    };

    prefetch(0);
    commit();
    __syncthreads();

    for (int c = 0; c < 64; ++c) {
        if (c + 1 < 64) prefetch(c + 1);

        // ---- M1: Sq^T[D][n]; softmax over n; -> PQ[n][D]
        f32x4 sq[4];
        {
            bf16x8 a0 = *(const bf16x8*)(WiB + swz128(w * 16 + li, g * 16));
            bf16x8 a1 = *(const bf16x8*)(WiB + swz128(w * 16 + li, 64 + g * 16));
#pragma unroll
            for (int tn = 0; tn < 4; ++tn) {
                bf16x8 b0 = *(const bf16x8*)(Qc + swz128(tn * 16 + li, g * 16));
                bf16x8 b1 = *(const bf16x8*)(Qc + swz128(tn * 16 + li, 64 + g * 16));
                f32x4 z = (f32x4)0.0f;
                z = __builtin_amdgcn_mfma_f32_16x16x32_bf16(a0, b0, z, 0, 0, 0);
                z = __builtin_amdgcn_mfma_f32_16x16x32_bf16(a1, b1, z, 0, 0, 0);
                sq[tn] = z;
            }
        }
#pragma unroll
        for (int r = 0; r < 4; ++r) {
            float m = fmaxf(fmaxf(sq[0][r], sq[1][r]), fmaxf(sq[2][r], sq[3][r]));
            m = fmaxf(m, __shfl_xor(m, 1)); m = fmaxf(m, __shfl_xor(m, 2));
            m = fmaxf(m, __shfl_xor(m, 4)); m = fmaxf(m, __shfl_xor(m, 8));
            float e0 = __expf(sq[0][r] - m), e1 = __expf(sq[1][r] - m);
            float e2 = __expf(sq[2][r] - m), e3 = __expf(sq[3][r] - m);
            float s = e0 + e1 + e2 + e3;
            s += __shfl_xor(s, 1); s += __shfl_xor(s, 2);
            s += __shfl_xor(s, 4); s += __shfl_xor(s, 8);
            float inv = 1.0f / s;
            sq[0][r] = e0 * inv; sq[1][r] = e1 * inv; sq[2][r] = e2 * inv; sq[3][r] = e3 * inv;
        }
#pragma unroll
        for (int tn = 0; tn < 4; ++tn) {
            int n = tn * 16 + li;
            uint2 pw;
            pw.x = (uint32_t)f2bf(sq[tn][0]) | ((uint32_t)f2bf(sq[tn][1]) << 16);
            pw.y = (uint32_t)f2bf(sq[tn][2]) | ((uint32_t)f2bf(sq[tn][3]) << 16);
            *(uint2*)(PQ + swz128(n, (w * 16 + g * 4) * 2)) = pw;
        }

        // ---- M2: Sk^T -> p^T in regs ----
        f32x4 pk[4];
        {
            bf16x8 a0 = *(const bf16x8*)(WiB + swz128(w * 16 + li, g * 16));
            bf16x8 a1 = *(const bf16x8*)(WiB + swz128(w * 16 + li, 64 + g * 16));
#pragma unroll
            for (int tn = 0; tn < 4; ++tn) {
                bf16x8 b0 = *(const bf16x8*)(Kc + swz128(tn * 16 + li, g * 16));
                bf16x8 b1 = *(const bf16x8*)(Kc + swz128(tn * 16 + li, 64 + g * 16));
                f32x4 z = (f32x4)0.0f;
                z = __builtin_amdgcn_mfma_f32_16x16x32_bf16(a0, b0, z, 0, 0, 0);
                z = __builtin_amdgcn_mfma_f32_16x16x32_bf16(a1, b1, z, 0, 0, 0);
                pk[tn] = z;
            }
        }
#pragma unroll
        for (int r = 0; r < 4; ++r) {
            float m = fmaxf(fmaxf(pk[0][r], pk[1][r]), fmaxf(pk[2][r], pk[3][r]));
            m = fmaxf(m, __shfl_xor(m, 1)); m = fmaxf(m, __shfl_xor(m, 2));
            m = fmaxf(m, __shfl_xor(m, 4)); m = fmaxf(m, __shfl_xor(m, 8));
            float e0 = __expf(pk[0][r] - m), e1 = __expf(pk[1][r] - m);
            float e2 = __expf(pk[2][r] - m), e3 = __expf(pk[3][r] - m);
            float s = e0 + e1 + e2 + e3;
            s += __shfl_xor(s, 1); s += __shfl_xor(s, 2);
            s += __shfl_xor(s, 4); s += __shfl_xor(s, 8);
            float inv = 1.0f / s;
            pk[0][r] = e0 * inv; pk[1][r] = e1 * inv; pk[2][r] = e2 * inv; pk[3][r] = e3 * inv;
        }

        // ---- M4': a^T[D][n] = sum_d Wo[D][d] v[n][d] ----
        f32x4 aT[4];
        {
            bf16x8 a0 = *(const bf16x8*)(WoB + swz128(w * 16 + li, g * 16));
            bf16x8 a1 = *(const bf16x8*)(WoB + swz128(w * 16 + li, 64 + g * 16));
#pragma unroll
            for (int tn = 0; tn < 4; ++tn) {
                bf16x8 b0 = *(const bf16x8*)(Vc + swz128(tn * 16 + li, g * 16));
                bf16x8 b1 = *(const bf16x8*)(Vc + swz128(tn * 16 + li, 64 + g * 16));
                f32x4 z = (f32x4)0.0f;
                z = __builtin_amdgcn_mfma_f32_16x16x32_bf16(a0, b0, z, 0, 0, 0);
                z = __builtin_amdgcn_mfma_f32_16x16x32_bf16(a1, b1, z, 0, 0, 0);
                aT[tn] = z;
            }
        }
#pragma unroll
        for (int tn = 0; tn < 4; ++tn) {
            f32x4 t4 = pk[tn] * aT[tn];
            float s_ = t4[0] + t4[1] + t4[2] + t4[3];
            s_ += __shfl_xor(s_, 16);
            s_ += __shfl_xor(s_, 32);
            if (g == 0) spart[w * 64 + tn * 16 + li] = s_;
        }
        __syncthreads();   // B: spart, PQ visible

#pragma unroll
        for (int tn = 0; tn < 4; ++tn) {
            int n = tn * 16 + li;
            float sn = spart[n] + spart[64 + n] + spart[128 + n] + spart[192 + n];
#pragma unroll
            for (int r = 0; r < 4; ++r) {
                int D = w * 16 + g * 4 + r;
                float gz = pk[tn][r] * (sn - aT[tn][r]);
                *(u16*)(GZT + swz128(D, n * 2)) = f2bf(gz);
                *(u16*)(PT + swz128(D, n * 2)) = f2bf(pk[tn][r]);
            }
        }
        __syncthreads();   // C: GZT, PT visible

        // ---- M3: o[n][d] = sum_D pq[n][D] Wo[D][d] ----
        f32x4 o4[4];
        {
            bf16x8 a0 = *(const bf16x8*)(PQ + swz128(w * 16 + li, g * 16));
            bf16x8 a1 = *(const bf16x8*)(PQ + swz128(w * 16 + li, 64 + g * 16));
#pragma unroll
            for (int tn = 0; tn < 4; ++tn) {
                bf16x8 b0 = *(const bf16x8*)(WoT + swz128(tn * 16 + li, g * 16));
                bf16x8 b1 = *(const bf16x8*)(WoT + swz128(tn * 16 + li, 64 + g * 16));
                f32x4 z = (f32x4)0.0f;
                z = __builtin_amdgcn_mfma_f32_16x16x32_bf16(a0, b0, z, 0, 0, 0);
                z = __builtin_amdgcn_mfma_f32_16x16x32_bf16(a1, b1, z, 0, 0, 0);
                o4[tn] = z;
            }
        }
        {
            const size_t obase = ((size_t)(b * 4096 + c * 64)) * 1024 + h * 64;
#pragma unroll
            for (int tn = 0; tn < 4; ++tn) {
                int d = tn * 16 + li;
#pragma unroll
                for (int r = 0; r < 4; ++r) {
                    int n = w * 16 + g * 4 + r;
                    ob[obase + (size_t)n * 1024 + d] = f2bf(o4[tn][r]);
                }
            }
        }
        // ---- M5: go[D][d] = sum_n p[n][D] v[n][d] ----
        f32x4 go[4];
        {
            bf16x8 a0 = *(const bf16x8*)(PT + swz128(w * 16 + li, g * 16));
            bf16x8 a1 = *(const bf16x8*)(PT + swz128(w * 16 + li, 64 + g * 16));
#pragma unroll
            for (int tn = 0; tn < 4; ++tn) {
                bf16x8 b0 = *(const bf16x8*)(VcT + swz128(tn * 16 + li, g * 16));
                bf16x8 b1 = *(const bf16x8*)(VcT + swz128(tn * 16 + li, 64 + g * 16));
                f32x4 z = (f32x4)0.0f;
                z = __builtin_amdgcn_mfma_f32_16x16x32_bf16(a0, b0, z, 0, 0, 0);
                z = __builtin_amdgcn_mfma_f32_16x16x32_bf16(a1, b1, z, 0, 0, 0);
                go[tn] = z;
            }
        }
        // ---- M6: gi[D][d] = sum_n gz[n][D] k[n][d] ----
        f32x4 gi[4];
        {
            bf16x8 a0 = *(const bf16x8*)(GZT + swz128(w * 16 + li, g * 16));
            bf16x8 a1 = *(const bf16x8*)(GZT + swz128(w * 16 + li, 64 + g * 16));
#pragma unroll
            for (int tn = 0; tn < 4; ++tn) {
                bf16x8 b0 = *(const bf16x8*)(KcT + swz128(tn * 16 + li, g * 16));
                bf16x8 b1 = *(const bf16x8*)(KcT + swz128(tn * 16 + li, 64 + g * 16));
                f32x4 z = (f32x4)0.0f;
                z = __builtin_amdgcn_mfma_f32_16x16x32_bf16(a0, b0, z, 0, 0, 0);
                z = __builtin_amdgcn_mfma_f32_16x16x32_bf16(a1, b1, z, 0, 0, 0);
                gi[tn] = z;
            }
        }
        __syncthreads();   // D: all reads of current-chunk LDS complete

        {
            float lin = lrc[c * 4 + 0], lout = lrc[c * 4 + 1];
            float win = lrc[c * 4 + 2], wout = lrc[c * 4 + 3];
#pragma unroll
            for (int tn = 0; tn < 4; ++tn) {
                int d = tn * 16 + li;
#pragma unroll
                for (int r = 0; r < 4; ++r) {
                    int D = w * 16 + g * 4 + r;
                    float nwi = win * WiF[D * 64 + d] - lin * gi[tn][r];
                    WiF[D * 64 + d] = nwi;
                    *(u16*)(WiB + swz128(D, d * 2)) = f2bf(nwi);
                    float nwo = wout * WoF[D * 64 + d] + lout * go[tn][r];
                    WoF[D * 64 + d] = nwo;
                    *(u16*)(WoB + swz128(D, d * 2)) = f2bf(nwo);
                    *(u16*)(WoT + swz128(d, D * 2)) = f2bf(nwo);
                }
            }
        }
        if (c + 1 < 64) commit();
        __syncthreads();   // A: next chunk ready
    }
}

// ---------------------------------------------------------------------------
// Kernel D: out[t][m] = sum_j o[t][j] * Wo[m][j]   (bf16 in, fp32 out)
// ---------------------------------------------------------------------------
__global__ __launch_bounds__(256) void out_proj_kernel(
    const u16* __restrict__ ob, const u16* __restrict__ wob, float* __restrict__ out)
{
    __shared__ __align__(16) char As[128 * 128];
    __shared__ __align__(16) char Bs[128 * 128];
    const int bn = blockIdx.x;            // 0..7
    const int bm = blockIdx.y;            // 0..127
    const int cb = bn * 128;
    const int rb = bm * 128;
    const int tid = threadIdx.x;
    const int lane = tid & 63;
    const int wv = tid >> 6;
    const int wr = (wv >> 1) * 64, wc = (wv & 1) * 64;
    const int li = lane & 15, g = lane >> 4;
    const int lr8 = lane >> 3, lc8 = lane & 7;

    f32x4 acc[4][4];
#pragma unroll
    for (int i = 0; i < 4; ++i)
#pragma unroll
        for (int j = 0; j < 4; ++j) acc[i][j] = (f32x4)0.0f;

    for (int k0 = 0; k0 < 1024; k0 += 64) {
        __syncthreads();
#pragma unroll
        for (int ld = 0; ld < 4; ++ld) {
            int r0 = wv * 32 + ld * 8;
            gload_lds16(ob + (size_t)(rb + r0 + lr8) * 1024 + k0 + lc8 * 8, As + r0 * 128);
            gload_lds16(wob + (size_t)(cb + r0 + lr8) * 1024 + k0 + lc8 * 8, Bs + r0 * 128);
        }
        __syncthreads();
#pragma unroll
        for (int ks = 0; ks < 2; ++ks) {
            bf16x8 af[4], bfr[4];
#pragma unroll
            for (int m = 0; m < 4; ++m)
                af[m] = *(const bf16x8*)(As + (wr + m * 16 + li) * 128 + ks * 64 + g * 16);
#pragma unroll
            for (int n = 0; n < 4; ++n)
                bfr[n] = *(const bf16x8*)(Bs + (wc + n * 16 + li) * 128 + ks * 64 + g * 16);
#pragma unroll
            for (int m = 0; m < 4; ++m)
#pragma unroll
                for (int n = 0; n < 4; ++n)
                    acc[m][n] = __builtin_amdgcn_mfma_f32_16x16x32_bf16(af[m], bfr[n], acc[m][n], 0, 0, 0);
        }
    }
#pragma unroll
    for (int m = 0; m < 4; ++m) {
        int t = rb + wr + m * 16 + g * 4;
#pragma unroll
        for (int r = 0; r < 4; ++r) {
#pragma unroll
            for (int n = 0; n < 4; ++n) {
                int col = cb + wc + n * 16 + li;
                out[(size_t)(t + r) * 1024 + col] = acc[m][n][r];
            }
        }
    }
}

// ---------------------------------------------------------------------------
extern "C" void kernel_launch(void* const* d_in, const int* in_sizes, int n_in,
                              void* d_out, int out_size, void* d_ws, size_t ws_size,
                              hipStream_t stream)
{
    const float* x     = (const float*)d_in[0];
    const float* Wq    = (const float*)d_in[1];
    const float* Wk    = (const float*)d_in[2];
    const float* Wv    = (const float*)d_in[3];
    const float* Wlr   = (const float*)d_in[4];
    const float* Wbeta = (const float*)d_in[5];
    const float* Wo    = (const float*)d_in[6];
    const float* Wi0   = (const float*)d_in[7];
    const float* Wo0   = (const float*)d_in[8];
    float* out = (float*)d_out;

    // d_out (64 MB fp32) doubles as scratch for the bf16 operands that are
    // dead before out_proj overwrites it: xb, wb(=Wq|Wk|Wv), wlb(=Wlr|Wbeta).
    char* od = (char*)d_out;
    u16* xb  = (u16*)(od);                 // 33,554,432 B
    u16* wb  = (u16*)(od + 33554432u);     //  6,291,456 B
    u16* wlb = (u16*)(od + 39845888u);     //    131,072 B

    char* ws = (char*)d_ws;
    u16* qb       = (u16*)(ws);
    u16* kb       = (u16*)(ws + 33554432u);
    u16* vb       = (u16*)(ws + 67108864u);
    u16* obuf     = (u16*)(ws + 100663296u);
    float* lrc_all = (float*)(ws + 134217728u);   // 65,536 B
    u16* wob      = (u16*)(ws + 134283264u);      // 2,097,152 B
    if (ws_size < 136380416u) return;

    convert_kernel<<<2048, 256, 0, stream>>>(x, Wq, Wk, Wv, Wo, Wlr, Wbeta,
                                             xb, wb, wob, wlb);
    proj_qkv_kernel<<<dim3(24, 128), 256, 0, stream>>>(xb, wb, qb, kb, vb);
    lrwd_kernel<<<128, 256, 0, stream>>>(xb, wlb, lrc_all);
    scan_kernel<<<64, 256, 0, stream>>>(qb, kb, vb, lrc_all, Wi0, Wo0, obuf);
    out_proj_kernel<<<dim3(8, 128), 256, 0, stream>>>(obuf, wob, out);
}